// Round 1
// baseline (1341.725 us; speedup 1.0000x reference)
//
#include <hip/hip_runtime.h>

#define B_ 64
#define T_ 256
#define DIN_ 1024
#define DOUT_ 1024

// -----------------------------------------------------------------------------
// GEMM: pre[t][o][b] (fp64) = sum_k x[b][t][k] * W[o][k] + bias[o]
// Block = (t0 fixed) x (o-tile of 128), covering all 64 b.
// Rows of A are x[(b*256 + t0)][:]  (stride 256 rows apart).
// fp32 loads -> convert to fp64 on LDS store -> fp64 FMA inner loop.
// -----------------------------------------------------------------------------
__global__ __launch_bounds__(256) void snn_gemm_f64(
    const float* __restrict__ x, const float* __restrict__ W,
    const float* __restrict__ bias, double* __restrict__ pre)
{
    __shared__ double As[16][64];    // [k][b]   8 KB  (reused as trans[16][64] in epilogue)
    __shared__ double Bs[16][128];   // [k][o]  16 KB

    const int t0 = blockIdx.x & 255;
    const int o0 = blockIdx.x >> 8;     // 0..7
    const int tid = threadIdx.x;
    const int to = tid & 15;            // o-group: o_local = to*8 + j
    const int tb = tid >> 4;            // b-group: b = tb*4 + i

    double acc[4][8];
#pragma unroll
    for (int i = 0; i < 4; ++i)
#pragma unroll
        for (int j = 0; j < 8; ++j) acc[i][j] = 0.0;

    // staging assignments
    const int arow = tid >> 2;           // 0..63  (= b)
    const int ak   = (tid & 3) * 4;      // 4 floats per thread for A
    const int orow = tid >> 1;           // 0..127 (= o_local)
    const int bk   = (tid & 1) * 8;      // 8 floats per thread for B

    const float* xg = x + (size_t)(t0 + 256 * arow) * DIN_ + ak;
    const float* wg = W + (size_t)(o0 * 128 + orow) * DIN_ + bk;

    for (int kk = 0; kk < DIN_; kk += 16) {
        float4 av  = *(const float4*)(xg + kk);
        float4 bv0 = *(const float4*)(wg + kk);
        float4 bv1 = *(const float4*)(wg + kk + 4);
        As[ak + 0][arow] = (double)av.x;
        As[ak + 1][arow] = (double)av.y;
        As[ak + 2][arow] = (double)av.z;
        As[ak + 3][arow] = (double)av.w;
        Bs[bk + 0][orow] = (double)bv0.x;
        Bs[bk + 1][orow] = (double)bv0.y;
        Bs[bk + 2][orow] = (double)bv0.z;
        Bs[bk + 3][orow] = (double)bv0.w;
        Bs[bk + 4][orow] = (double)bv1.x;
        Bs[bk + 5][orow] = (double)bv1.y;
        Bs[bk + 6][orow] = (double)bv1.z;
        Bs[bk + 7][orow] = (double)bv1.w;
        __syncthreads();
#pragma unroll
        for (int k = 0; k < 16; ++k) {
            double a[4], b[8];
#pragma unroll
            for (int i = 0; i < 4; ++i) a[i] = As[k][tb * 4 + i];
#pragma unroll
            for (int j = 0; j < 8; ++j) b[j] = Bs[k][to * 8 + j];
#pragma unroll
            for (int i = 0; i < 4; ++i)
#pragma unroll
                for (int j = 0; j < 8; ++j)
                    acc[i][j] += a[i] * b[j];   // v_fma_f64
        }
        __syncthreads();
    }

    // epilogue: add bias, LDS-transpose 16-o chunks so stores are b-contiguous
    double biasd[8];
#pragma unroll
    for (int j = 0; j < 8; ++j) biasd[j] = (double)bias[o0 * 128 + to * 8 + j];

    double (*trans)[64] = As;   // reuse As (exact shape [16][64])

    for (int c = 0; c < 8; ++c) {
        __syncthreads();
        if ((to >> 1) == c) {
            const int ol = (to & 1) * 8;   // row offset inside chunk
#pragma unroll
            for (int j = 0; j < 8; ++j)
#pragma unroll
                for (int i = 0; i < 4; ++i)
                    trans[ol + j][tb * 4 + i] = acc[i][j] + biasd[j];
        }
        __syncthreads();
#pragma unroll
        for (int q = 0; q < 4; ++q) {
            const int idx = tid + 256 * q;
            const int b  = idx & 63;
            const int oc = idx >> 6;       // 0..15
            pre[(size_t)(t0 * DOUT_ + o0 * 128 + c * 16 + oc) * 64 + b] = trans[oc][b];
        }
    }
}

// -----------------------------------------------------------------------------
// Scan: one wave per output unit o, lane = b. Batch-mean via ballot+popcount.
// Barrier-free; 4-deep load grouping to keep HBM loads in flight.
// pre layout [t][o][b]; spikes written to spT [(t*O+o)][b] (or direct fallback).
// -----------------------------------------------------------------------------
__global__ __launch_bounds__(256) void snn_scan(
    const double* __restrict__ pre, const float* __restrict__ thr_in,
    float* __restrict__ spT, float* __restrict__ outD)
{
    const int wid  = (blockIdx.x * blockDim.x + threadIdx.x) >> 6;
    const int lane = threadIdx.x & 63;
    if (wid >= DOUT_) return;
    const int o = wid;

    double mem = 0.0;
    double thr = (double)thr_in[o];
    const double* p = pre + (size_t)o * 64 + lane;

    for (int t = 0; t < T_; t += 4) {
        double pv[4];
#pragma unroll
        for (int j = 0; j < 4; ++j)
            pv[j] = p[(size_t)(t + j) * (DOUT_ * 64)];
#pragma unroll
        for (int j = 0; j < 4; ++j) {
            mem += pv[j];
            const bool s = (mem >= thr);
            const unsigned long long msk = __ballot(s);
            const int cnt = __popcll(msk);
            thr += 0.05 * ((double)cnt * (1.0 / 64.0) - 0.5);
            const float sf = s ? 1.0f : 0.0f;
            if (spT) {
                spT[(size_t)(t + j) * (DOUT_ * 64) + (size_t)o * 64 + lane] = sf;
            } else {
                outD[(size_t)lane * (T_ * DOUT_) + (size_t)(t + j) * DOUT_ + o] = sf;
            }
            mem = s ? 0.0 : mem;
        }
    }
}

// -----------------------------------------------------------------------------
// Transpose: spT [(t*O+o)][64 b] -> out [64 b][(t*O+o)]   (64x64 LDS tiles)
// -----------------------------------------------------------------------------
__global__ __launch_bounds__(256) void snn_transpose(
    const float* __restrict__ spT, float* __restrict__ out)
{
    __shared__ float tile[64][65];
    const int R0   = blockIdx.x * 64;        // r = t*DOUT_ + o
    const int lane = threadIdx.x & 63;
    const int grp  = threadIdx.x >> 6;       // 0..3
#pragma unroll
    for (int rr = grp; rr < 64; rr += 4)
        tile[rr][lane] = spT[(size_t)(R0 + rr) * 64 + lane];
    __syncthreads();
#pragma unroll
    for (int bq = grp; bq < 64; bq += 4)
        out[(size_t)bq * (T_ * DOUT_) + R0 + lane] = tile[lane][bq];
}

extern "C" void kernel_launch(void* const* d_in, const int* in_sizes, int n_in,
                              void* d_out, int out_size, void* d_ws, size_t ws_size,
                              hipStream_t stream) {
    const float* x    = (const float*)d_in[0];   // [64][256][1024]
    const float* W    = (const float*)d_in[1];   // [1024][1024]
    const float* bias = (const float*)d_in[2];   // [1024]
    const float* thr  = (const float*)d_in[3];   // [1024]
    float* out = (float*)d_out;                  // [64][256][1024]

    double* pre = (double*)d_ws;
    const size_t preBytes = (size_t)T_ * DOUT_ * B_ * sizeof(double);  // 128 MiB
    const size_t spBytes  = (size_t)T_ * DOUT_ * B_ * sizeof(float);   //  64 MiB
    const bool two_stage = (ws_size >= preBytes + spBytes);
    float* spT = two_stage ? (float*)((char*)d_ws + preBytes) : nullptr;

    snn_gemm_f64<<<2048, 256, 0, stream>>>(x, W, bias, pre);
    snn_scan<<<256, 256, 0, stream>>>(pre, thr, spT, two_stage ? nullptr : out);
    if (two_stage)
        snn_transpose<<<4096, 256, 0, stream>>>(spT, out);
}

// Round 2
// 927.330 us; speedup vs baseline: 1.4469x; 1.4469x over previous
//
#include <hip/hip_runtime.h>

#define B_ 64
#define T_ 256
#define DIN_ 1024
#define DOUT_ 1024

// -----------------------------------------------------------------------------
// GEMM: pre[t][o][b] (fp64) = sum_k x[b][t][k] * W[o][k] + bias[o]
// Block = (t0 fixed) x (o-tile of 128), covering all 64 b.
// Thread (to,tb) owns b = tb*4+i (i<4), o = o0*128 + j*16 + to (j<8).
// The stride-16 o-mapping makes every inner-loop B read 16 consecutive
// doubles (bank-conflict-free, 4-fold broadcast across the wave).
// -----------------------------------------------------------------------------
__global__ __launch_bounds__(256) void snn_gemm_f64(
    const float* __restrict__ x, const float* __restrict__ W,
    const float* __restrict__ bias, double* __restrict__ pre)
{
    __shared__ double As[16][66];    // [k][b]  +2 pad: keeps 16B align for b128,
                                     //          breaks epilogue write conflicts
    __shared__ double Bs[16][128];   // [k][o_local]

    const int t0 = blockIdx.x & 255;
    const int o0 = blockIdx.x >> 8;     // 0..7
    const int tid = threadIdx.x;
    const int to = tid & 15;            // o_local = j*16 + to
    const int tb = tid >> 4;            // b = tb*4 + i

    double acc[4][8];
#pragma unroll
    for (int i = 0; i < 4; ++i)
#pragma unroll
        for (int j = 0; j < 8; ++j) acc[i][j] = 0.0;

    // staging assignments: A = 64 rows(b) x 16 k ; B = 128 rows(o) x 16 k
    const int arow = tid >> 2;           // 0..63  (= b)
    const int ak   = (tid & 3) * 4;      // 4 floats per thread for A
    const int worow = tid >> 2;          // 0..63  (W rows worow, worow+64)
    const int wk    = (tid & 3) * 4;     // 4 floats per row-chunk

    const float* xg  = x + (size_t)(t0 + 256 * arow) * DIN_ + ak;
    const float* wg0 = W + (size_t)(o0 * 128 + worow) * DIN_ + wk;
    const float* wg1 = W + (size_t)(o0 * 128 + worow + 64) * DIN_ + wk;

    float4 av  = *(const float4*)(xg);
    float4 bv0 = *(const float4*)(wg0);
    float4 bv1 = *(const float4*)(wg1);

    for (int kk = 0; kk < DIN_; kk += 16) {
        As[ak + 0][arow] = (double)av.x;
        As[ak + 1][arow] = (double)av.y;
        As[ak + 2][arow] = (double)av.z;
        As[ak + 3][arow] = (double)av.w;
        Bs[wk + 0][worow] = (double)bv0.x;
        Bs[wk + 1][worow] = (double)bv0.y;
        Bs[wk + 2][worow] = (double)bv0.z;
        Bs[wk + 3][worow] = (double)bv0.w;
        Bs[wk + 0][worow + 64] = (double)bv1.x;
        Bs[wk + 1][worow + 64] = (double)bv1.y;
        Bs[wk + 2][worow + 64] = (double)bv1.z;
        Bs[wk + 3][worow + 64] = (double)bv1.w;
        __syncthreads();

        // prefetch next tile while this one computes
        if (kk + 16 < DIN_) {
            av  = *(const float4*)(xg + kk + 16);
            bv0 = *(const float4*)(wg0 + kk + 16);
            bv1 = *(const float4*)(wg1 + kk + 16);
        }

#pragma unroll
        for (int k = 0; k < 16; ++k) {
            double a[4], b[8];
#pragma unroll
            for (int i = 0; i < 4; ++i) a[i] = As[k][tb * 4 + i];   // 2x ds_read_b128
#pragma unroll
            for (int j = 0; j < 8; ++j) b[j] = Bs[k][j * 16 + to];  // lane-consecutive
#pragma unroll
            for (int i = 0; i < 4; ++i)
#pragma unroll
                for (int j = 0; j < 8; ++j)
                    acc[i][j] += a[i] * b[j];   // v_fma_f64
        }
        __syncthreads();
    }

    // epilogue: add bias, LDS-transpose 16-o chunks so stores are b-contiguous
    double biasd[8];
#pragma unroll
    for (int j = 0; j < 8; ++j) biasd[j] = (double)bias[o0 * 128 + j * 16 + to];

    double (*trans)[66] = As;   // reuse As

    for (int c = 0; c < 8; ++c) {
        __syncthreads();
        // chunk c holds o_local = c*16 + to from every thread
#pragma unroll
        for (int i = 0; i < 4; ++i)
            trans[to][tb * 4 + i] = acc[i][c] + biasd[c];
        __syncthreads();
#pragma unroll
        for (int q = 0; q < 4; ++q) {
            const int idx = tid + 256 * q;
            const int b  = idx & 63;
            const int oc = idx >> 6;       // 0..15
            pre[(size_t)(t0 * DOUT_ + o0 * 128 + c * 16 + oc) * 64 + b] = trans[oc][b];
        }
    }
}

// -----------------------------------------------------------------------------
// Scan: one wave per output unit o, lane = b. Batch-mean via ballot+popcount.
// Barrier-free; 4-deep load grouping to keep HBM loads in flight.
// pre layout [t][o][b]; spikes written to spT [(t*O+o)][b] (or direct fallback).
// -----------------------------------------------------------------------------
__global__ __launch_bounds__(256) void snn_scan(
    const double* __restrict__ pre, const float* __restrict__ thr_in,
    float* __restrict__ spT, float* __restrict__ outD)
{
    const int wid  = (blockIdx.x * blockDim.x + threadIdx.x) >> 6;
    const int lane = threadIdx.x & 63;
    if (wid >= DOUT_) return;
    const int o = wid;

    double mem = 0.0;
    double thr = (double)thr_in[o];
    const double* p = pre + (size_t)o * 64 + lane;

    for (int t = 0; t < T_; t += 4) {
        double pv[4];
#pragma unroll
        for (int j = 0; j < 4; ++j)
            pv[j] = p[(size_t)(t + j) * (DOUT_ * 64)];
#pragma unroll
        for (int j = 0; j < 4; ++j) {
            mem += pv[j];
            const bool s = (mem >= thr);
            const unsigned long long msk = __ballot(s);
            const int cnt = __popcll(msk);
            thr += 0.05 * ((double)cnt * (1.0 / 64.0) - 0.5);
            const float sf = s ? 1.0f : 0.0f;
            if (spT) {
                spT[(size_t)(t + j) * (DOUT_ * 64) + (size_t)o * 64 + lane] = sf;
            } else {
                outD[(size_t)lane * (T_ * DOUT_) + (size_t)(t + j) * DOUT_ + o] = sf;
            }
            mem = s ? 0.0 : mem;
        }
    }
}

// -----------------------------------------------------------------------------
// Transpose: spT [(t*O+o)][64 b] -> out [64 b][(t*O+o)]   (64x64 LDS tiles)
// -----------------------------------------------------------------------------
__global__ __launch_bounds__(256) void snn_transpose(
    const float* __restrict__ spT, float* __restrict__ out)
{
    __shared__ float tile[64][65];
    const int R0   = blockIdx.x * 64;        // r = t*DOUT_ + o
    const int lane = threadIdx.x & 63;
    const int grp  = threadIdx.x >> 6;       // 0..3
#pragma unroll
    for (int rr = grp; rr < 64; rr += 4)
        tile[rr][lane] = spT[(size_t)(R0 + rr) * 64 + lane];
    __syncthreads();
#pragma unroll
    for (int bq = grp; bq < 64; bq += 4)
        out[(size_t)bq * (T_ * DOUT_) + R0 + lane] = tile[lane][bq];
}

extern "C" void kernel_launch(void* const* d_in, const int* in_sizes, int n_in,
                              void* d_out, int out_size, void* d_ws, size_t ws_size,
                              hipStream_t stream) {
    const float* x    = (const float*)d_in[0];   // [64][256][1024]
    const float* W    = (const float*)d_in[1];   // [1024][1024]
    const float* bias = (const float*)d_in[2];   // [1024]
    const float* thr  = (const float*)d_in[3];   // [1024]
    float* out = (float*)d_out;                  // [64][256][1024]

    double* pre = (double*)d_ws;
    const size_t preBytes = (size_t)T_ * DOUT_ * B_ * sizeof(double);  // 128 MiB
    const size_t spBytes  = (size_t)T_ * DOUT_ * B_ * sizeof(float);   //  64 MiB
    const bool two_stage = (ws_size >= preBytes + spBytes);
    float* spT = two_stage ? (float*)((char*)d_ws + preBytes) : nullptr;

    snn_gemm_f64<<<2048, 256, 0, stream>>>(x, W, bias, pre);
    snn_scan<<<256, 256, 0, stream>>>(pre, thr, spT, two_stage ? nullptr : out);
    if (two_stage)
        snn_transpose<<<4096, 256, 0, stream>>>(spT, out);
}